// Round 11
// baseline (261.458 us; speedup 1.0000x reference)
//
#include <hip/hip_runtime.h>

#define E_EDGES   1000000
#define NNODES    2048
#define HCH       128
#define KP        136            // A/w1t row stride bf16: 128 z + 4 attr + bias + 3 zero
#define TILE      64
#define NTILES    (E_EDGES / TILE)   // 15625 exact
#define NSPREAD   8
#define GRID_GEMM 1024           // 4 blocks/CU; bid%8 -> XCD (round-robin dispatch)
#define BPB       128            // blocks per bin (GRID_GEMM/8)
#define ZVEC      (32 * 2048 * 64 / 4)
#define ZBLK      2048
#define WBLK      66             // 66*256 = 132*128 w1t transpose elements
#define NBIN      8              // bins by src>>13: 1 MB of zb each (fits XCD L2)
#define CBLK      512            // count/scatter blocks

typedef short  shortx8 __attribute__((ext_vector_type(8)));
typedef float  floatx4 __attribute__((ext_vector_type(4)));

__device__ __forceinline__ unsigned short f2bf(float f) {
  union { float f; unsigned int u; } v; v.f = f;
  unsigned int r = (v.u + 0x7fffu + ((v.u >> 16) & 1u)) >> 16;
  return (unsigned short)r;
}
__device__ __forceinline__ void cfence() { asm volatile("" ::: "memory"); }
// lgkm-only barrier: LDS writes visible; vmem prefetches stay in flight.
__device__ __forceinline__ void bar_lds() {
  asm volatile("s_waitcnt lgkmcnt(0)" ::: "memory");
  __builtin_amdgcn_s_barrier();
  cfence();
}
__device__ __forceinline__ unsigned pack_rows(int s, int d) {
  unsigned rs = (unsigned)s & 0xFFFFu;
  unsigned rd = (unsigned)(((s & ~(NNODES - 1)) | (d & (NNODES - 1)))) & 0xFFFFu;
  return rs | (rd << 16);
}

// ---------------------------------------------------------------- prep ----
// zb cast, w1t transpose, gstats zero, per-block bin histogram (plain stores).
__global__ void k_prep(const float* __restrict__ z, const float* __restrict__ W1,
                       const float* __restrict__ b1, const int* __restrict__ ei,
                       unsigned short* __restrict__ zb, unsigned short* __restrict__ w1t,
                       float* __restrict__ gstats, int* __restrict__ cnt) {
  int bid = blockIdx.x;
  if (bid < ZBLK) {
    const float4* z4 = (const float4*)z;
    ushort4* zb4 = (ushort4*)zb;
    for (int i = bid * 256 + threadIdx.x; i < ZVEC; i += ZBLK * 256) {
      float4 v = z4[i];
      ushort4 o;
      o.x = f2bf(v.x); o.y = f2bf(v.y); o.z = f2bf(v.z); o.w = f2bf(v.w);
      zb4[i] = o;
    }
  } else if (bid < ZBLK + WBLK) {
    int idx = (bid - ZBLK) * 256 + threadIdx.x;   // 0..16895 = 132*128
    int k = idx >> 7, n = idx & 127;              // coalesced read of W1
    w1t[n * KP + k] = f2bf(W1[idx]);
  } else if (bid == ZBLK + WBLK) {
    int tid = threadIdx.x;
    if (tid < 512) {   // pad k=132..135: bias at 132, zeros after
      int n = tid >> 2, kp = 132 + (tid & 3);
      w1t[n * KP + kp] = (kp == 132) ? f2bf(b1[n]) : (unsigned short)0;
    }
    for (int i = tid; i < NSPREAD * 2 * HCH; i += 256) gstats[i] = 0.f;
  } else {
    // per-block histogram of src>>13 (no global atomics)
    __shared__ int lh[NBIN];
    int tid = threadIdx.x;
    int cb = bid - (ZBLK + WBLK + 1);
    if (tid < NBIN) lh[tid] = 0;
    __syncthreads();
    for (int e = cb * 256 + tid; e < E_EDGES; e += CBLK * 256)
      atomicAdd(&lh[((unsigned)ei[e]) >> 13], 1);
    __syncthreads();
    if (tid < NBIN) cnt[cb * NBIN + tid] = lh[tid];
  }
}

// ---------------------------------------------------------------- scan ----
// S[b] = bin starts; base[blk][b] = scatter base per (block,bin); binTile[] =
// tile-range boundaries (tile t belongs to bin of its FIRST edge).
__global__ void k_scan(const int* __restrict__ cnt, int* __restrict__ base,
                       int* __restrict__ binTile) {
  __shared__ int tot[NBIN], S[NBIN + 1];
  int b = threadIdx.x;
  if (b < NBIN) {
    int t = 0;
    for (int blk = 0; blk < CBLK; ++blk) t += cnt[blk * NBIN + b];
    tot[b] = t;
  }
  __syncthreads();
  if (b == 0) {
    int a = 0;
    for (int i = 0; i < NBIN; ++i) { S[i] = a; a += tot[i]; }
    S[NBIN] = a;                                   // = E_EDGES
    binTile[0] = 0;
    for (int i = 1; i <= NBIN; ++i) binTile[i] = (S[i] + 63) >> 6;  // [NBIN]=15625
  }
  __syncthreads();
  if (b < NBIN) {
    int run = S[b];
    for (int blk = 0; blk < CBLK; ++blk) {
      base[blk * NBIN + b] = run;
      run += cnt[blk * NBIN + b];
    }
  }
}

// ------------------------------------------------------------- scatter ----
// recs[slot] = {packed_rows, attr01 bf16x2, attr23 bf16x2, orig_idx};
// slots via LDS atomics only (same per-block edge subset as the histogram).
__global__ __launch_bounds__(256)
void k_scatter(const int* __restrict__ ei, const float* __restrict__ attr,
               const int* __restrict__ base, uint4* __restrict__ recs) {
  __shared__ int lcnt[NBIN];
  int tid = threadIdx.x, bid = blockIdx.x;
  if (tid < NBIN) lcnt[tid] = base[bid * NBIN + tid];
  __syncthreads();
  for (int e = bid * 256 + tid; e < E_EDGES; e += CBLK * 256) {
    int s = ei[e], d = ei[E_EDGES + e];
    float4 a = ((const float4*)attr)[e];
    int b = ((unsigned)s) >> 13;
    int slot = atomicAdd(&lcnt[b], 1);
    uint4 r;
    r.x = pack_rows(s, d);
    r.y = (unsigned)f2bf(a.x) | ((unsigned)f2bf(a.y) << 16);
    r.z = (unsigned)f2bf(a.z) | ((unsigned)f2bf(a.w) << 16);
    r.w = (unsigned)e;
    recs[slot] = r;
  }
}

// ---------------------------------------------------------------- gemm ----
// R9 inner structure (occupancy-4, channel-quarter waves, coalesced staging,
// acc-reuse, one lgkm-only barrier/tile) on bin-bucketed records with
// XCD-pinned tile assignment: bin = bid%8 (= XCD under round-robin dispatch),
// so each XCD gathers only from its own 1-MB zb slice -> L2-resident.
// ostash is TRIPLE-buffered: its tail read happens AFTER the tile barrier, so
// the overwriting stage-top must be >=2 barriers later (2-buffer races — R10 bug).
template<bool OUT>
__global__ __launch_bounds__(256, 4)
void k_gemm(const unsigned short* __restrict__ zb,
            const unsigned short* __restrict__ w1t,
            const uint4* __restrict__ recs,
            const int* __restrict__ binTile,
            float* __restrict__ gstats,
            const float* __restrict__ gamma,
            const float* __restrict__ beta,
            const float* __restrict__ W2,
            const float* __restrict__ b2,
            float* __restrict__ out) {
  __shared__ __align__(16) unsigned short A[2][TILE * KP];   // 34816 B
  __shared__ float po[2][4][TILE];                           //  2048 B
  __shared__ int ostash[3][TILE];                            //   768 B

  const int tid  = threadIdx.x;
  const int lane = tid & 63;
  const int w    = tid >> 6;      // channel quarter
  const int l15  = lane & 15;
  const int quad = lane >> 4;
  const int ea   = w * 8 + (lane >> 3);   // first edge this thread stages
  const int eb   = ea + 32;               // second edge
  const int ch   = lane & 7;              // 16B chunk within a 128B row

  // ---- B fragments: 2 n-tiles x 5 k-steps for this wave's 32 channels
  shortx8 bfr[2][4], bfr4[2];
#pragma unroll
  for (int nt = 0; nt < 2; ++nt) {
    const unsigned short* bp = w1t + (w * 32 + nt * 16 + l15) * KP;
#pragma unroll
    for (int kk = 0; kk < 4; ++kk)
      bfr[nt][kk] = *(const shortx8*)(bp + kk * 32 + quad * 8);
    bfr4[nt] = (quad == 0) ? *(const shortx8*)(bp + 128)
                           : (shortx8){0, 0, 0, 0, 0, 0, 0, 0};
  }

  float eaf[2], ebb[2], ew2[2], b2v = 0.f;
  float ssum[2] = {0.f, 0.f}, ssq[2] = {0.f, 0.f};
  if (OUT) {
#pragma unroll
    for (int nt = 0; nt < 2; ++nt) {
      int c = w * 32 + nt * 16 + l15;
      float S = 0.f, Q = 0.f;
#pragma unroll
      for (int i = 0; i < NSPREAD; ++i) {
        S += gstats[i * 2 * HCH + c];
        Q += gstats[i * 2 * HCH + HCH + c];
      }
      float mu   = S * (1.0f / (float)E_EDGES);
      float var  = Q * (1.0f / (float)E_EDGES) - mu * mu;
      float rstd = rsqrtf(var + 1e-5f);
      float a = gamma[c] * rstd;
      eaf[nt] = a;
      ebb[nt] = beta[c] - mu * a;
      ew2[nt] = W2[c];
    }
    b2v = b2[0];
  }

  // ---- one-time: constant bias block (k=132..135) in both buffers
  if (tid < 128) {
    int b = tid >> 6, r = tid & 63;
    ushort4 bl; bl.x = 0x3F80; bl.y = 0; bl.z = 0; bl.w = 0;
    *(ushort4*)(&A[b][0] + r * KP + 132) = bl;
  }

  // ---- bin-pinned tile range
  const int x    = blockIdx.x & 7;               // bin == XCD
  const int t0i  = binTile[x] + (blockIdx.x >> 3);
  const int tEnd = binTile[x + 1];
  if (t0i >= tEnd) return;                       // empty: zero stats contribution

  auto stage = [&](uint4 ra, uint4 rb, const uint4& h0, const uint4& h1,
                   const uint4& h2, const uint4& h3, int buf, int os) {
    *(uint4*)(&A[buf][0] + ea * KP + ch * 8)      = h0;
    *(uint4*)(&A[buf][0] + eb * KP + ch * 8)      = h1;
    *(uint4*)(&A[buf][0] + ea * KP + 64 + ch * 8) = h2;
    *(uint4*)(&A[buf][0] + eb * KP + 64 + ch * 8) = h3;
    if (ch == 0) {
      ushort4 aA; aA.x = (unsigned short)ra.y; aA.y = (unsigned short)(ra.y >> 16);
      aA.z = (unsigned short)ra.z; aA.w = (unsigned short)(ra.z >> 16);
      *(ushort4*)(&A[buf][0] + ea * KP + 128) = aA;
      ushort4 aB; aB.x = (unsigned short)rb.y; aB.y = (unsigned short)(rb.y >> 16);
      aB.z = (unsigned short)rb.z; aB.w = (unsigned short)(rb.z >> 16);
      *(ushort4*)(&A[buf][0] + eb * KP + 128) = aB;
      ostash[os][ea] = (int)ra.w;
      ostash[os][eb] = (int)rb.w;
    }
  };

  // ---- prologue: stage t0; prefetch gather(t1); recs(t2) in flight
  uint4 g0, g1, g2, g3;          // gather of next tile (to stage)
  uint4 recSa, recSb;            // recs of next tile (attr/orig at staging)
  uint4 recFa, recFb;            // recs of tile after next (gather source)
  {
    uint4 ra = recs[t0i * TILE + ea];
    uint4 rb = recs[t0i * TILE + eb];
    unsigned r0 = ra.x & 0xFFFFu, r1 = rb.x & 0xFFFFu;
    unsigned r2 = ra.x >> 16,     r3 = rb.x >> 16;
    uint4 h0 = *(const uint4*)(zb + (size_t)r0 * 64 + ch * 8);
    uint4 h1 = *(const uint4*)(zb + (size_t)r1 * 64 + ch * 8);
    uint4 h2 = *(const uint4*)(zb + (size_t)r2 * 64 + ch * 8);
    uint4 h3 = *(const uint4*)(zb + (size_t)r3 * 64 + ch * 8);
    stage(ra, rb, h0, h1, h2, h3, 0, 0);
    int t1 = t0i + BPB; if (t1 > tEnd - 1) t1 = tEnd - 1;
    recSa = recs[t1 * TILE + ea];
    recSb = recs[t1 * TILE + eb];
    r0 = recSa.x & 0xFFFFu; r1 = recSb.x & 0xFFFFu;
    r2 = recSa.x >> 16;     r3 = recSb.x >> 16;
    g0 = *(const uint4*)(zb + (size_t)r0 * 64 + ch * 8);
    g1 = *(const uint4*)(zb + (size_t)r1 * 64 + ch * 8);
    g2 = *(const uint4*)(zb + (size_t)r2 * 64 + ch * 8);
    g3 = *(const uint4*)(zb + (size_t)r3 * 64 + ch * 8);
    int t2 = t0i + 2 * BPB; if (t2 > tEnd - 1) t2 = tEnd - 1;
    recFa = recs[t2 * TILE + ea];
    recFb = recs[t2 * TILE + eb];
  }
  bar_lds();

  int pp = 0, sl = 0, osr = 0;
  for (int tile = t0i; ; ) {
    const int tnext = tile + BPB;
    const bool more = tnext < tEnd;
    const int osw = (osr == 2) ? 0 : osr + 1;   // ostash slot for NEXT tile

    if (more) {
      stage(recSa, recSb, g0, g1, g2, g3, pp ^ 1, osw);
      // gather t+2 from in-flight recF; then load recs t+3
      unsigned r0 = recFa.x & 0xFFFFu, r1 = recFb.x & 0xFFFFu;
      unsigned r2 = recFa.x >> 16,     r3 = recFb.x >> 16;
      g0 = *(const uint4*)(zb + (size_t)r0 * 64 + ch * 8);
      g1 = *(const uint4*)(zb + (size_t)r1 * 64 + ch * 8);
      g2 = *(const uint4*)(zb + (size_t)r2 * 64 + ch * 8);
      g3 = *(const uint4*)(zb + (size_t)r3 * 64 + ch * 8);
      recSa = recFa; recSb = recFb;
      int tn3 = tile + 3 * BPB; if (tn3 > tEnd - 1) tn3 = tEnd - 1;
      recFa = recs[tn3 * TILE + ea];
      recFb = recs[tn3 * TILE + eb];
    }

    // ---- MFMA: 4 edge m-tiles sequentially, acc[2] reused
    const unsigned short* Ar = &A[pp][0];
#pragma unroll
    for (int mt = 0; mt < 4; ++mt) {
      const unsigned short* ap = Ar + (mt * 16 + l15) * KP;
      shortx8 afr[4], a4;
#pragma unroll
      for (int kk = 0; kk < 4; ++kk)
        afr[kk] = *(const shortx8*)(ap + kk * 32 + quad * 8);
      a4 = (quad == 0) ? *(const shortx8*)(ap + 128)
                       : (shortx8){0, 0, 0, 0, 0, 0, 0, 0};

      floatx4 acc[2];
      acc[0] = (floatx4){0.f, 0.f, 0.f, 0.f};
      acc[1] = (floatx4){0.f, 0.f, 0.f, 0.f};
#pragma unroll
      for (int kk = 0; kk < 4; ++kk)
#pragma unroll
        for (int nt = 0; nt < 2; ++nt)
          acc[nt] = __builtin_amdgcn_mfma_f32_16x16x32_bf16(
              afr[kk], bfr[nt][kk], acc[nt], 0, 0, 0);
#pragma unroll
      for (int nt = 0; nt < 2; ++nt)
        acc[nt] = __builtin_amdgcn_mfma_f32_16x16x32_bf16(
            a4, bfr4[nt], acc[nt], 0, 0, 0);

      // per-mt epilogue. C/D: col=l15 (channel), row=quad*4+r (edge in m-tile)
      if (!OUT) {
#pragma unroll
        for (int nt = 0; nt < 2; ++nt) {
          float s = 0.f, qq = 0.f;
#pragma unroll
          for (int r = 0; r < 4; ++r) {
            float h = acc[nt][r];
            s += h; qq += h * h;
          }
          ssum[nt] += s; ssq[nt] += qq;
        }
      } else {
#pragma unroll
        for (int r = 0; r < 4; ++r) {
          float t = 0.f;
#pragma unroll
          for (int nt = 0; nt < 2; ++nt) {
            float h = acc[nt][r];
            float p = fmaf(eaf[nt], h, ebb[nt]);
            p = (p >= 0.f) ? p : 0.2f * p;
            t = fmaf(ew2[nt], p, t);
          }
          t += __shfl_xor(t, 1);
          t += __shfl_xor(t, 2);
          t += __shfl_xor(t, 4);
          t += __shfl_xor(t, 8);     // sum over this wave's 32 channels
          if (l15 == 0)
            po[sl][w][mt * 16 + quad * 4 + r] = t;
        }
      }
    }

    if (more || OUT) bar_lds();      // A[pp^1]+po+ostash visible; gathers in flight

    if (OUT && tid < TILE)
      out[ostash[osr][tid]] = po[sl][0][tid] + po[sl][1][tid] +
                              po[sl][2][tid] + po[sl][3][tid] + b2v;

    if (!more) break;
    pp ^= 1; sl ^= 1; osr = osw;
    tile = tnext;
  }

  if (!OUT) {   // flush: quads hold disjoint edge subsets; reduce, one atomic set
    float* gs = gstats + (blockIdx.x & (NSPREAD - 1)) * 2 * HCH;
#pragma unroll
    for (int nt = 0; nt < 2; ++nt) {
      float s = ssum[nt], qq = ssq[nt];
      s += __shfl_xor(s, 16); s += __shfl_xor(s, 32);
      qq += __shfl_xor(qq, 16); qq += __shfl_xor(qq, 32);
      if (quad == 0) {
        int c = w * 32 + nt * 16 + l15;
        atomicAdd(&gs[c], s);
        atomicAdd(&gs[HCH + c], qq);
      }
    }
  }
}

// -------------------------------------------------------------- launch ----
extern "C" void kernel_launch(void* const* d_in, const int* in_sizes, int n_in,
                              void* d_out, int out_size, void* d_ws, size_t ws_size,
                              hipStream_t stream) {
  const float* z     = (const float*)d_in[0];
  const float* attr  = (const float*)d_in[1];
  const float* W1    = (const float*)d_in[2];
  const float* b1    = (const float*)d_in[3];
  const float* gamma = (const float*)d_in[4];
  const float* beta  = (const float*)d_in[5];
  const float* W2    = (const float*)d_in[6];
  const float* b2    = (const float*)d_in[7];
  const int*   ei    = (const int*)d_in[8];
  float* out = (float*)d_out;

  char* ws = (char*)d_ws;
  unsigned short* zb  = (unsigned short*)ws;                 //  8,388,608 B
  unsigned short* w1t = (unsigned short*)(ws + 8388608);     //     34,816 B
  float* gstats       = (float*)(ws + 8423424);              //      8,192 B
  int* cnt            = (int*)(ws + 8431616);                //     16,384 B
  int* base           = (int*)(ws + 8448000);                //     16,384 B
  int* binTile        = (int*)(ws + 8464384);                //         64 B
  uint4* recs         = (uint4*)(ws + 8464448);              // 16,000,000 B
  // total ws: ~24.5 MB

  k_prep<<<ZBLK + WBLK + 1 + CBLK, 256, 0, stream>>>(z, W1, b1, ei, zb, w1t,
                                                     gstats, cnt);
  k_scan<<<1, 64, 0, stream>>>(cnt, base, binTile);
  k_scatter<<<CBLK, 256, 0, stream>>>(ei, attr, base, recs);
  k_gemm<false><<<GRID_GEMM, 256, 0, stream>>>(zb, w1t, recs, binTile, gstats,
                                               gamma, beta, W2, b2, nullptr);
  k_gemm<true><<<GRID_GEMM, 256, 0, stream>>>(zb, w1t, recs, binTile, gstats,
                                              gamma, beta, W2, b2, out);
}